// Round 7
// baseline (560.273 us; speedup 1.0000x reference)
//
#include <hip/hip_runtime.h>
#include <math.h>

#define SCALE_F 0.0721687836487032f  // 192^-0.5

typedef __attribute__((ext_vector_type(8))) short bf16x8;
typedef __attribute__((ext_vector_type(4))) float f32x4;
typedef __attribute__((ext_vector_type(4))) unsigned short u16x4;

static __device__ __forceinline__ short f2bf(float f) {
  unsigned u = __float_as_uint(f);
  u += 0x7fffu + ((u >> 16) & 1u);   // RNE
  return (short)(u >> 16);
}

// async global->LDS, 16B per lane (m97-verified path)
static __device__ __forceinline__ void gl_lds16(const void* g, void* l) {
  __builtin_amdgcn_global_load_lds((const __attribute__((address_space(1))) void*)g,
                                   (__attribute__((address_space(3))) void*)l, 16, 0, 0);
}

// ---------------------------------------------------------------------------
// bf16 MFMA GEMM, BK=64 variant of the m97 2-barrier template.
// LDS layout [kk][128][32] (two BK=32 halves): every 1KB DMA chunk covers
// 16 rows x 32 cols exactly as the R1-verified BK=32 version -> identical
// global coalescing (16x64B segments) and identical frag-read bank pattern;
// only the barrier count per K halves.
// MODE 0: fp32 out row-major [M][N]
// MODE 4: merged down-proj: col<1536 -> q_lat fp32; col>=1536 -> kvf fp32
// ---------------------------------------------------------------------------
template <int MODE>
__global__ __launch_bounds__(256) void gemm_mfma(
    const short* __restrict__ A, const short* __restrict__ W,
    void* __restrict__ Cout, int N, int K,
    const float* __restrict__ cosb, const float* __restrict__ sinb,
    short* __restrict__ out2)
{
  __shared__ __align__(16) short As[2 * 128 * 32];   // [kk][128][32], 16 KB
  __shared__ __align__(16) short Ws[2 * 128 * 32];
  const int tid = threadIdx.x;
  const int wv = tid >> 6, lane = tid & 63;
  const int quad = lane >> 4, n16 = lane & 15;
  const int bm = blockIdx.y * 128, bn = blockIdx.x * 128;
  const int wr = (wv >> 1) * 64, wc = (wv & 1) * 64;

  f32x4 acc[4][4];
  #pragma unroll
  for (int i = 0; i < 4; ++i)
    #pragma unroll
    for (int j = 0; j < 4; ++j) acc[i][j] = (f32x4){0.f, 0.f, 0.f, 0.f};

  // chunk c = wv*4+i: kk = c>>3, row-block = c&7; lane -> row lane>>2, col (lane&3)*8
  const short* aS[4]; const short* wS[4]; short* aD[4]; short* wD[4];
  #pragma unroll
  for (int i = 0; i < 4; ++i) {
    int c = wv * 4 + i, kk = c >> 3, rb = c & 7;
    aS[i] = A + (size_t)(bm + rb * 16 + (lane >> 2)) * K + kk * 32 + (lane & 3) * 8;
    wS[i] = W + (size_t)(bn + rb * 16 + (lane >> 2)) * K + kk * 32 + (lane & 3) * 8;
    aD[i] = &As[c * 512 + lane * 8];
    wD[i] = &Ws[c * 512 + lane * 8];
  }

  for (int k0 = 0; k0 < K; k0 += 64) {
    #pragma unroll
    for (int i = 0; i < 4; ++i) {
      gl_lds16(aS[i], aD[i]);
      gl_lds16(wS[i], wD[i]);
      aS[i] += 64; wS[i] += 64;
    }
    __syncthreads();

    #pragma unroll
    for (int kk = 0; kk < 2; ++kk) {
      bf16x8 af[4], wf[4];
      #pragma unroll
      for (int i = 0; i < 4; ++i) {
        af[i] = *(const bf16x8*)&As[kk * 4096 + (wr + i * 16 + n16) * 32 + quad * 8];
        wf[i] = *(const bf16x8*)&Ws[kk * 4096 + (wc + i * 16 + n16) * 32 + quad * 8];
      }
      #pragma unroll
      for (int i = 0; i < 4; ++i)
        #pragma unroll
        for (int j = 0; j < 4; ++j)
          acc[i][j] = __builtin_amdgcn_mfma_f32_16x16x32_bf16(af[i], wf[j], acc[i][j], 0, 0, 0);
    }
    __syncthreads();
  }

  if (MODE == 0) {
    #pragma unroll
    for (int i = 0; i < 4; ++i)
      #pragma unroll
      for (int r = 0; r < 4; ++r) {
        size_t row = (size_t)(bm + wr + i * 16 + quad * 4 + r);
        #pragma unroll
        for (int j = 0; j < 4; ++j)
          ((float*)Cout)[row * N + bn + wc + j * 16 + n16] = acc[i][j][r];
      }
  } else {
    // MODE 4: merged down-proj split output (tile-uniform: col<1536 -> q_lat)
    float* qlat = (float*)Cout;
    float* kvf  = (float*)out2;
    #pragma unroll
    for (int i = 0; i < 4; ++i)
      #pragma unroll
      for (int r = 0; r < 4; ++r) {
        size_t row = (size_t)(bm + wr + i * 16 + quad * 4 + r);
        #pragma unroll
        for (int j = 0; j < 4; ++j) {
          int col = bn + wc + j * 16 + n16;
          if (col < 1536) qlat[row * 1536 + col] = acc[i][j][r];
          else            kvf[row * 640 + (col - 1536)] = acc[i][j][r];
        }
      }
  }
}

// ---------------------------------------------------------------------------
// combined up-proj GEMM (BK=64 template, co-launched):
//   blocks x<24 : q_up  (N=3072, K=1536) -> rope+scale -> Qb (b,h,s,192)
//   blocks x>=24: kv_up (N=4096, K=512)  -> Kb nope / Vt scatter; nope tiles
//                 also copy Kb rope cols from krope (fused krope_fill)
// Epilogues byte-identical to the R4/R6-verified ones. No extra LDS.
// ---------------------------------------------------------------------------
__global__ __launch_bounds__(256) void gemm_up(
    const short* __restrict__ Aq, const short* __restrict__ Wq,
    short* __restrict__ Qb,
    const float* __restrict__ cosb, const float* __restrict__ sinb,
    const short* __restrict__ Akv, const short* __restrict__ Wkv,
    short* __restrict__ Kb, short* __restrict__ Vtb,
    const short* __restrict__ krope)
{
  __shared__ __align__(16) short As[2 * 128 * 32];
  __shared__ __align__(16) short Ws[2 * 128 * 32];

  const bool isQ = blockIdx.x < 24;
  const short* A = isQ ? Aq : Akv;
  const short* W = isQ ? Wq : Wkv;
  const int K = isQ ? 1536 : 512;
  const int bx = isQ ? blockIdx.x : (blockIdx.x - 24);

  const int tid = threadIdx.x;
  const int wv = tid >> 6, lane = tid & 63;
  const int quad = lane >> 4, n16 = lane & 15;
  const int bm = blockIdx.y * 128, bn = bx * 128;
  const int wr = (wv >> 1) * 64, wc = (wv & 1) * 64;

  f32x4 acc[4][4];
  #pragma unroll
  for (int i = 0; i < 4; ++i)
    #pragma unroll
    for (int j = 0; j < 4; ++j) acc[i][j] = (f32x4){0.f, 0.f, 0.f, 0.f};

  const short* aS[4]; const short* wS[4]; short* aD[4]; short* wD[4];
  #pragma unroll
  for (int i = 0; i < 4; ++i) {
    int c = wv * 4 + i, kk = c >> 3, rb = c & 7;
    aS[i] = A + (size_t)(bm + rb * 16 + (lane >> 2)) * K + kk * 32 + (lane & 3) * 8;
    wS[i] = W + (size_t)(bn + rb * 16 + (lane >> 2)) * K + kk * 32 + (lane & 3) * 8;
    aD[i] = &As[c * 512 + lane * 8];
    wD[i] = &Ws[c * 512 + lane * 8];
  }

  for (int k0 = 0; k0 < K; k0 += 64) {
    #pragma unroll
    for (int i = 0; i < 4; ++i) {
      gl_lds16(aS[i], aD[i]);
      gl_lds16(wS[i], wD[i]);
      aS[i] += 64; wS[i] += 64;
    }
    __syncthreads();

    #pragma unroll
    for (int kk = 0; kk < 2; ++kk) {
      bf16x8 af[4], wf[4];
      #pragma unroll
      for (int i = 0; i < 4; ++i) {
        af[i] = *(const bf16x8*)&As[kk * 4096 + (wr + i * 16 + n16) * 32 + quad * 8];
        wf[i] = *(const bf16x8*)&Ws[kk * 4096 + (wc + i * 16 + n16) * 32 + quad * 8];
      }
      #pragma unroll
      for (int i = 0; i < 4; ++i)
        #pragma unroll
        for (int j = 0; j < 4; ++j)
          acc[i][j] = __builtin_amdgcn_mfma_f32_16x16x32_bf16(af[i], wf[j], acc[i][j], 0, 0, 0);
    }
    __syncthreads();
  }

  if (isQ) {
    // q_up: rope last 64 of each 192-head, scale, pack to (b,h,s,192)
    #pragma unroll
    for (int i = 0; i < 4; ++i)
      #pragma unroll
      for (int r = 0; r < 4; ++r) {
        int m = bm + wr + i * 16 + quad * 4 + r;
        int bb = m >> 11, s = m & 2047;
        #pragma unroll
        for (int j = 0; j < 4; ++j) {
          int col = bn + wc + j * 16 + n16;
          int h = col / 192, c = col - h * 192;
          float v = acc[i][j][r];
          if (c >= 128) {
            int jr = c - 128;
            float part = acc[i][j ^ 2][r];   // partner col = col +/- 32 (in-wave)
            float cs = cosb[(size_t)m * 64 + jr], sn = sinb[(size_t)m * 64 + jr];
            v = (jr < 32) ? (v * cs - part * sn) : (v * cs + part * sn);
          }
          Qb[(((size_t)(bb * 16 + h)) * 2048 + s) * 192 + c] = f2bf(v * SCALE_F);
        }
      }
  } else {
    // kv_up: head = col>>8; c<128 -> Kb nope, c>=128 -> Vt transposed scatter
    #pragma unroll
    for (int i = 0; i < 4; ++i)
      #pragma unroll
      for (int r = 0; r < 4; ++r) {
        int m = bm + wr + i * 16 + quad * 4 + r;
        int bb = m >> 11, s = m & 2047;
        #pragma unroll
        for (int j = 0; j < 4; ++j) {
          int col = bn + wc + j * 16 + n16;
          int h = col >> 8, c = col & 255;
          short v = f2bf(acc[i][j][r]);
          if (c < 128)
            Kb[(((size_t)(bb * 16 + h)) * 2048 + s) * 192 + c] = v;
          else
            Vtb[((size_t)(bb * 16 + h) * 128 + (c - 128)) * 2048 + s] = v;
        }
      }
    // fused krope_fill: nope tiles copy rope cols for (head h, rows bm..bm+127)
    if ((bn & 255) == 0) {
      const int h = bn >> 8;
      const int bb = bm >> 11, sb = bm & 2047;
      const int rr = tid >> 1, half = tid & 1;
      const short* src = krope + (size_t)(bm + rr) * 64 + half * 32;
      short* dst = Kb + (((size_t)(bb * 16 + h)) * 2048 + sb + rr) * 192 + 128 + half * 32;
      #pragma unroll
      for (int k = 0; k < 4; ++k)
        *(bf16x8*)(dst + k * 8) = *(const bf16x8*)(src + k * 8);
    }
  }
}

// ---------------------------------------------------------------------------
// fused fp32 -> bf16 cast of hidden + all 5 weights (one launch)
// ---------------------------------------------------------------------------
__global__ __launch_bounds__(256) void cast_all(
    const float* __restrict__ hidden, const float* __restrict__ Wqd,
    const float* __restrict__ Wqu, const float* __restrict__ Wkvu,
    const float* __restrict__ Wo, const float* __restrict__ Wkvd,
    short* __restrict__ hb, short* __restrict__ Wqd_b, short* __restrict__ Wqu_b,
    short* __restrict__ Wkvu_b, short* __restrict__ Wo_b, short* __restrict__ Wkvd_b)
{
  int blk = blockIdx.x;
  const float* src; short* dst; int i;
  if (blk < 8192)       { src = hidden; dst = hb;     i = (blk * 256 + threadIdx.x) * 4; }
  else if (blk < 11264) { src = Wqd;  dst = Wqd_b;  i = ((blk - 8192) * 256 + threadIdx.x) * 4; }
  else if (blk < 15872) { src = Wqu;  dst = Wqu_b;  i = ((blk - 11264) * 256 + threadIdx.x) * 4; }
  else if (blk < 17920) { src = Wkvu; dst = Wkvu_b; i = ((blk - 15872) * 256 + threadIdx.x) * 4; }
  else if (blk < 22016) { src = Wo;   dst = Wo_b;   i = ((blk - 17920) * 256 + threadIdx.x) * 4; }
  else {
    i = ((blk - 22016) * 256 + threadIdx.x) * 4;
    int r = i >> 11;
    short4 o = {0, 0, 0, 0};
    if (r < 576) {
      float4 v = *(const float4*)(Wkvd + i);
      o.x = f2bf(v.x); o.y = f2bf(v.y); o.z = f2bf(v.z); o.w = f2bf(v.w);
    }
    *(short4*)(Wkvd_b + i) = o;
    return;
  }
  float4 v = *(const float4*)(src + i);
  short4 o = { f2bf(v.x), f2bf(v.y), f2bf(v.z), f2bf(v.w) };
  *(short4*)(dst + i) = o;
}

// ---------------------------------------------------------------------------
// merged RMSNorm: blocks <4096 -> q_lat (C=1536); blocks >=4096 -> kv + rope
// ---------------------------------------------------------------------------
__global__ __launch_bounds__(256) void rmsnorm_both(
    const float* __restrict__ q_lat, const float* __restrict__ q_gamma,
    short* __restrict__ q_lat_b,
    const float* __restrict__ kvf, const float* __restrict__ kv_gamma,
    const float* __restrict__ cosb, const float* __restrict__ sinb,
    short* __restrict__ ckv, short* __restrict__ kr)
{
  const int tid = threadIdx.x;
  __shared__ float red[4];
  if (blockIdx.x < 4096) {
    const int m = blockIdx.x;
    const float* x = q_lat + (size_t)m * 1536;
    short* y = q_lat_b + (size_t)m * 1536;
    float ss = 0.f;
    for (int c = tid * 4; c < 1536; c += 1024) {
      float4 v = *(const float4*)(x + c);
      ss += v.x * v.x + v.y * v.y + v.z * v.z + v.w * v.w;
    }
    #pragma unroll
    for (int off = 32; off > 0; off >>= 1) ss += __shfl_down(ss, off, 64);
    if ((tid & 63) == 0) red[tid >> 6] = ss;
    __syncthreads();
    float tot = red[0] + red[1] + red[2] + red[3];
    float scale = rsqrtf(tot / 1536.f + 1e-6f);
    for (int c = tid * 4; c < 1536; c += 1024) {
      float4 v = *(const float4*)(x + c);
      float4 g = *(const float4*)(q_gamma + c);
      short4 o = { f2bf(v.x * scale * g.x), f2bf(v.y * scale * g.y),
                   f2bf(v.z * scale * g.z), f2bf(v.w * scale * g.w) };
      *(short4*)(y + c) = o;
    }
  } else {
    const int m = blockIdx.x - 4096;
    const float* x = kvf + (size_t)m * 640;
    short* y = ckv + (size_t)m * 512;
    float ss = 0.f;
    for (int c = tid * 4; c < 512; c += 1024) {
      float4 v = *(const float4*)(x + c);
      ss += v.x * v.x + v.y * v.y + v.z * v.z + v.w * v.w;
    }
    #pragma unroll
    for (int off = 32; off > 0; off >>= 1) ss += __shfl_down(ss, off, 64);
    if ((tid & 63) == 0) red[tid >> 6] = ss;
    __syncthreads();
    float tot = red[0] + red[1] + red[2] + red[3];
    float scale = rsqrtf(tot / 512.f + 1e-6f);
    for (int c = tid * 4; c < 512; c += 1024) {
      float4 v = *(const float4*)(x + c);
      float4 g = *(const float4*)(kv_gamma + c);
      short4 o = { f2bf(v.x * scale * g.x), f2bf(v.y * scale * g.y),
                   f2bf(v.z * scale * g.z), f2bf(v.w * scale * g.w) };
      *(short4*)(y + c) = o;
    }
    if (tid < 32) {
      const float* cb = cosb + (size_t)m * 64;
      const float* sb = sinb + (size_t)m * 64;
      float x1 = x[512 + tid], x2 = x[512 + tid + 32];
      kr[(size_t)m * 64 + tid]      = f2bf(x1 * cb[tid] - x2 * sb[tid]);
      kr[(size_t)m * 64 + tid + 32] = f2bf(x2 * cb[tid + 32] + x1 * sb[tid + 32]);
    }
  }
}

// ---------------------------------------------------------------------------
// MFMA flash attention v10: split-kt balanced schedule (R4-verified, 81 us;
// R6 chain-split reverted — it measured +3 us).
// ---------------------------------------------------------------------------
#define PSTR 72

__global__ __launch_bounds__(512) void flash_mfma(
    const short* __restrict__ Qb, const short* __restrict__ Kb,
    const short* __restrict__ Vt, short* __restrict__ attnb)
{
  __shared__ __align__(16) short KVs[2][40 * 512];   // per group: 24 K + 16 V chunks (80 KB)
  __shared__ __align__(16) short Ps[8][32 * PSTR];   // 36.9 KB   (total 116.9 KB)

  const int h = blockIdx.x;                          // XCD locality: id%8 = h%8
  const int p = blockIdx.y;                          // pair index 0..7
  const int b = blockIdx.z;
  const int bh = b * 16 + h;
  const int tid = threadIdx.x;
  const int wave = tid >> 6, lane = tid & 63;
  const int grp = wave >> 2, w4 = wave & 3;          // grp0 heavy / grp1 light->heavy
  const int quad = lane >> 4, n16 = lane & 15;
  const int lq = lane >> 2, lr = lane & 3;           // staging lane split
  const int qt_h = 15 - p;
  const int L = 2 * p + 2;                           // light-tile iteration count
  const int NIT = 17;                                // iterations for every wave

  int qw = (grp ? p : qt_h) * 128 + w4 * 32;         // current tile q-window

  const short* kS[6]; short* kD[6];
  #pragma unroll
  for (int u = 0; u < 6; ++u) {
    kS[u] = Kb + ((size_t)bh * 2048 + w4 * 16 + lq) * 192 + u * 32 + lr * 8;
    kD[u] = &KVs[grp][(w4 * 6 + u) * 512 + lane * 8];
  }
  const short* vS[4]; short* vD[4];
  #pragma unroll
  for (int u = 0; u < 4; ++u) {
    int ci = w4 * 4 + u, ks = ci >> 3, vt = ci & 7;
    vS[u] = Vt + ((size_t)bh * 128 + vt * 16 + lq) * 2048 + ks * 32 + lr * 8;
    vD[u] = &KVs[grp][(24 + ci) * 512 + lane * 8];
  }

  bf16x8 aQ[2][6];
  #pragma unroll
  for (int rg = 0; rg < 2; ++rg) {
    const short* qp = Qb + ((size_t)bh * 2048 + qw + rg * 16 + n16) * 192 + quad * 8;
    #pragma unroll
    for (int t = 0; t < 6; ++t) aQ[rg][t] = *(const bf16x8*)(qp + t * 32);
  }

  f32x4 O[2][8];
  #pragma unroll
  for (int rg = 0; rg < 2; ++rg)
    #pragma unroll
    for (int i = 0; i < 8; ++i) O[rg][i] = (f32x4){0.f, 0.f, 0.f, 0.f};
  float lp[2] = {0.f, 0.f};

  short* pw = &Ps[wave][0];

  {
    #pragma unroll
    for (int u = 0; u < 6; ++u) gl_lds16(kS[u], kD[u]);
    #pragma unroll
    for (int u = 0; u < 4; ++u) gl_lds16(vS[u], vD[u]);
  }

  for (int j = 0; j < NIT; ++j) {
    __syncthreads();   // stage(j) complete (barrier drains vmcnt)

    if (grp == 1 && j == L) {
      #pragma unroll
      for (int rg = 0; rg < 2; ++rg) {
        float l = lp[rg];
        l += __shfl_xor(l, 16);
        l += __shfl_xor(l, 32);
        float inv_l[4];
        #pragma unroll
        for (int r = 0; r < 4; ++r) inv_l[r] = 1.f / __shfl(l, quad * 4 + r);
        #pragma unroll
        for (int vt = 0; vt < 8; ++vt)
          #pragma unroll
          for (int r = 0; r < 4; ++r) {
            size_t m = (size_t)b * 2048 + qw + rg * 16 + quad * 4 + r;
            attnb[(m * 16 + h) * 128 + vt * 16 + n16] = f2bf(O[rg][vt][r] * inv_l[r]);
          }
      }
      #pragma unroll
      for (int rg = 0; rg < 2; ++rg)
        #pragma unroll
        for (int i = 0; i < 8; ++i) O[rg][i] = (f32x4){0.f, 0.f, 0.f, 0.f};
      lp[0] = 0.f; lp[1] = 0.f;
      qw = qt_h * 128 + w4 * 32;
      #pragma unroll
      for (int rg = 0; rg < 2; ++rg) {
        const short* qp = Qb + ((size_t)bh * 2048 + qw + rg * 16 + n16) * 192 + quad * 8;
        #pragma unroll
        for (int t = 0; t < 6; ++t) aQ[rg][t] = *(const bf16x8*)(qp + t * 32);
      }
    }

    const int kt = (grp == 0) ? j : (j < L ? j : 17 + j - L);

    if (kt * 64 <= qw + 31) {
      float s[4][2][4];
      bool act[4];
      const bool tail = (kt * 64 + 63 > qw);
      #pragma unroll
      for (int ct = 0; ct < 4; ++ct) {
        act[ct] = (kt * 64 + ct * 16 <= qw + 31);
        if (act[ct]) {
          f32x4 a0 = (f32x4){0.f, 0.f, 0.f, 0.f};
          f32x4 a1 = (f32x4){0.f, 0.f, 0.f, 0.f};
          #pragma unroll
          for (int t = 0; t < 6; ++t) {
            bf16x8 ak = *(const bf16x8*)&KVs[grp][(ct * 6 + t) * 512 + n16 * 32 + quad * 8];
            a0 = __builtin_amdgcn_mfma_f32_16x16x32_bf16(ak, aQ[0][t], a0, 0, 0, 0);
            a1 = __builtin_amdgcn_mfma_f32_16x16x32_bf16(ak, aQ[1][t], a1, 0, 0, 0);
          }
          #pragma unroll
          for (int r = 0; r < 4; ++r) { s[ct][0][r] = a0[r]; s[ct][1][r] = a1[r]; }
        }
      }

      #pragma unroll
      for (int rg = 0; rg < 2; ++rg) {
        const int q = qw + rg * 16 + n16;
        #pragma unroll
        for (int ct = 0; ct < 4; ++ct) {
          u16x4 pk;
          #pragma unroll
          for (int r = 0; r < 4; ++r) {
            float v = 0.f;
            if (act[ct]) {
              v = __expf(s[ct][rg][r]);
              if (tail) {
                int key = kt * 64 + ct * 16 + quad * 4 + r;
                if (key > q) v = 0.f;
              }
            }
            lp[rg] += v;
            pk[r] = (unsigned short)f2bf(v);
          }
          *(u16x4*)&pw[(rg * 16 + n16) * PSTR + ct * 16 + quad * 4] = pk;
        }
      }

      #pragma unroll
      for (int ks = 0; ks < 2; ++ks) {
        if (kt * 64 + ks * 32 <= qw + 31) {
          bf16x8 aP0 = *(const bf16x8*)&pw[(n16) * PSTR + ks * 32 + quad * 8];
          bf16x8 aP1 = *(const bf16x8*)&pw[(16 + n16) * PSTR + ks * 32 + quad * 8];
          #pragma unroll
          for (int vt = 0; vt < 8; ++vt) {
            bf16x8 bV = *(const bf16x8*)&KVs[grp][(24 + ks * 8 + vt) * 512 + n16 * 32 + quad * 8];
            O[0][vt] = __builtin_amdgcn_mfma_f32_16x16x32_bf16(aP0, bV, O[0][vt], 0, 0, 0);
            O[1][vt] = __builtin_amdgcn_mfma_f32_16x16x32_bf16(aP1, bV, O[1][vt], 0, 0, 0);
          }
        }
      }
    }

    __syncthreads();   // readers of KVs[grp] done

    if (j + 1 < NIT) {
      const int jn = j + 1;
      const int ktn = (grp == 0) ? jn : (jn < L ? jn : 17 + jn - L);
      const size_t ka = (size_t)ktn * (64 * 192);
      const size_t va = (size_t)ktn * 64;
      #pragma unroll
      for (int u = 0; u < 6; ++u) gl_lds16(kS[u] + ka, kD[u]);
      #pragma unroll
      for (int u = 0; u < 4; ++u) gl_lds16(vS[u] + va, vD[u]);
    }
  }

  // ---- epilogue: combine grp1's heavy partial into grp0, store heavy ----
  float* xO = (float*)&KVs[0][0];
  float* xl = (float*)&Ps[0][0];
  const int xb = w4 * 4160 + lane * 65;      // stride 65 -> conflict-free
  if (grp == 1) {
    #pragma unroll
    for (int rg = 0; rg < 2; ++rg)
      #pragma unroll
      for (int vt = 0; vt < 8; ++vt)
        #pragma unroll
        for (int r = 0; r < 4; ++r)
          xO[xb + rg * 32 + vt * 4 + r] = O[rg][vt][r];
    xl[w4 * 128 + lane * 2 + 0] = lp[0];
    xl[w4 * 128 + lane * 2 + 1] = lp[1];
  }
  __syncthreads();
  if (grp == 0) {
    #pragma unroll
    for (int rg = 0; rg < 2; ++rg)
      #pragma unroll
      for (int vt = 0; vt < 8; ++vt)
        #pragma unroll
        for (int r = 0; r < 4; ++r)
          O[rg][vt][r] += xO[xb + rg * 32 + vt * 4 + r];
    lp[0] += xl[w4 * 128 + lane * 2 + 0];
    lp[1] += xl[w4 * 128 + lane * 2 + 1];

    #pragma unroll
    for (int rg = 0; rg < 2; ++rg) {
      float l = lp[rg];
      l += __shfl_xor(l, 16);
      l += __shfl_xor(l, 32);
      float inv_l[4];
      #pragma unroll
      for (int r = 0; r < 4; ++r) inv_l[r] = 1.f / __shfl(l, quad * 4 + r);
      #pragma unroll
      for (int vt = 0; vt < 8; ++vt)
        #pragma unroll
        for (int r = 0; r < 4; ++r) {
          size_t m = (size_t)b * 2048 + qw + rg * 16 + quad * 4 + r;
          attnb[(m * 16 + h) * 128 + vt * 16 + n16] = f2bf(O[rg][vt][r] * inv_l[r]);
        }
    }
  }
}

// ---------------------------------------------------------------------------
extern "C" void kernel_launch(void* const* d_in, const int* in_sizes, int n_in,
                              void* d_out, int out_size, void* d_ws, size_t ws_size,
                              hipStream_t stream)
{
  const float* hidden   = (const float*)d_in[0];
  const float* cosb     = (const float*)d_in[1];
  const float* sinb     = (const float*)d_in[2];
  const float* Wq_down  = (const float*)d_in[3];
  const float* q_gamma  = (const float*)d_in[4];
  const float* Wq_up    = (const float*)d_in[5];
  const float* Wkv_down = (const float*)d_in[6];
  const float* kv_gamma = (const float*)d_in[7];
  const float* Wkv_up   = (const float*)d_in[8];
  const float* Wo       = (const float*)d_in[9];
  float* out = (float*)d_out;

  // ---- workspace (117 MB, aliased; liveness unchanged) ----
  char* base = (char*)d_ws;
  short* hb  = (short*)base;
  float* kvf = (float*)(base + 16777216);
  short* Qb  = (short*)base;
  char* pB = base + 27262976;
  short* Wqd_b  = (short*)pB;                       // [2176][2048] with Wkvd_b
  short* Wkvd_b = (short*)(pB + 6291456);
  short* Wqu_b  = (short*)(pB + 8912896);
  short* Wkvu_b = (short*)(pB + 18350080);
  short* Wo_b   = (short*)(pB + 22544384);
  char* pC = pB + 30932992;
  float* q_lat = (float*)pC;
  short* Kb    = (short*)pC;
  char* pD = pC + 25165824;
  short* q_lat_b = (short*)pD;
  short* ckv_b   = (short*)(pD + 12582912);
  short* krope_b = (short*)(pD + 16777216);
  short* attn_b  = (short*)pD;
  char* pE = pD + 17301504;
  short* Vt = (short*)pE;

  dim3 blk(256);

  cast_all<<<23296, blk, 0, stream>>>(hidden, Wq_down, Wq_up, Wkv_up, Wo, Wkv_down,
                                      hb, Wqd_b, Wqu_b, Wkvu_b, Wo_b, Wkvd_b);

  // merged down-proj: N=2176 (Wqd_b|Wkvd_b contiguous), split fp32 outputs
  gemm_mfma<4><<<dim3(17, 32), blk, 0, stream>>>(hb, Wqd_b, q_lat, 2176, 2048,
                                                 nullptr, nullptr, (short*)kvf);

  rmsnorm_both<<<8192, blk, 0, stream>>>(q_lat, q_gamma, q_lat_b,
                                         kvf, kv_gamma, cosb, sinb, ckv_b, krope_b);

  // co-launched up-proj: x<24 -> q_up (K=1536), x>=24 -> kv_up (K=512)
  gemm_up<<<dim3(56, 32), blk, 0, stream>>>(q_lat_b, Wqu_b, Qb, cosb, sinb,
                                            ckv_b, Wkvu_b, Kb, Vt, krope_b);

  flash_mfma<<<dim3(16, 8, 2), dim3(512), 0, stream>>>(Qb, Kb, Vt, attn_b);
  gemm_mfma<0><<<dim3(16, 32), blk, 0, stream>>>(attn_b, Wo_b, out, 2048, 2048,
                                                 nullptr, nullptr, nullptr);
}

// Round 8
// 495.031 us; speedup vs baseline: 1.1318x; 1.1318x over previous
//
#include <hip/hip_runtime.h>
#include <math.h>

#define SCALE_F 0.0721687836487032f  // 192^-0.5

typedef __attribute__((ext_vector_type(8))) short bf16x8;
typedef __attribute__((ext_vector_type(4))) float f32x4;
typedef __attribute__((ext_vector_type(4))) unsigned short u16x4;

static __device__ __forceinline__ short f2bf(float f) {
  unsigned u = __float_as_uint(f);
  u += 0x7fffu + ((u >> 16) & 1u);   // RNE
  return (short)(u >> 16);
}

// async global->LDS, 16B per lane (m97-verified path)
static __device__ __forceinline__ void gl_lds16(const void* g, void* l) {
  __builtin_amdgcn_global_load_lds((const __attribute__((address_space(1))) void*)g,
                                   (__attribute__((address_space(3))) void*)l, 16, 0, 0);
}

// ---------------------------------------------------------------------------
// bf16 MFMA GEMM, BK=64 variant of the m97 2-barrier template (separate
// launches per GEMM — co-launch twice-falsified R5/R7).
// LDS layout [kk][128][32] (two BK=32 halves): every 1KB DMA chunk covers
// 16 rows x 32 cols exactly as the R1-verified BK=32 version -> identical
// global coalescing (16x64B segments) and identical frag-read bank pattern;
// only the barrier count per K halves.
// MODE 0: fp32 out row-major [M][N]
// MODE 2: q_up fused rope+scale+pack -> Qb (b,h,s,192) bf16   (N=3072)
// MODE 3: kv_up fused split -> Kb nope cols + Vt transposed; nope tiles also
//         fill Kb rope cols from krope (passed via sinb) -> krope_fill fused
// MODE 4: merged down-proj: col<1536 -> q_lat fp32; col>=1536 -> kvf fp32
// ---------------------------------------------------------------------------
template <int MODE>
__global__ __launch_bounds__(256) void gemm_mfma(
    const short* __restrict__ A, const short* __restrict__ W,
    void* __restrict__ Cout, int N, int K,
    const float* __restrict__ cosb, const float* __restrict__ sinb,
    short* __restrict__ out2)
{
  __shared__ __align__(16) short As[2 * 128 * 32];   // [kk][128][32], 16 KB
  __shared__ __align__(16) short Ws[2 * 128 * 32];
  const int tid = threadIdx.x;
  const int wv = tid >> 6, lane = tid & 63;
  const int quad = lane >> 4, n16 = lane & 15;
  const int bm = blockIdx.y * 128, bn = blockIdx.x * 128;
  const int wr = (wv >> 1) * 64, wc = (wv & 1) * 64;

  f32x4 acc[4][4];
  #pragma unroll
  for (int i = 0; i < 4; ++i)
    #pragma unroll
    for (int j = 0; j < 4; ++j) acc[i][j] = (f32x4){0.f, 0.f, 0.f, 0.f};

  // chunk c = wv*4+i: kk = c>>3, row-block = c&7; lane -> row lane>>2, col (lane&3)*8
  const short* aS[4]; const short* wS[4]; short* aD[4]; short* wD[4];
  #pragma unroll
  for (int i = 0; i < 4; ++i) {
    int c = wv * 4 + i, kk = c >> 3, rb = c & 7;
    aS[i] = A + (size_t)(bm + rb * 16 + (lane >> 2)) * K + kk * 32 + (lane & 3) * 8;
    wS[i] = W + (size_t)(bn + rb * 16 + (lane >> 2)) * K + kk * 32 + (lane & 3) * 8;
    aD[i] = &As[c * 512 + lane * 8];
    wD[i] = &Ws[c * 512 + lane * 8];
  }

  for (int k0 = 0; k0 < K; k0 += 64) {
    #pragma unroll
    for (int i = 0; i < 4; ++i) {
      gl_lds16(aS[i], aD[i]);
      gl_lds16(wS[i], wD[i]);
      aS[i] += 64; wS[i] += 64;
    }
    __syncthreads();

    #pragma unroll
    for (int kk = 0; kk < 2; ++kk) {
      bf16x8 af[4], wf[4];
      #pragma unroll
      for (int i = 0; i < 4; ++i) {
        af[i] = *(const bf16x8*)&As[kk * 4096 + (wr + i * 16 + n16) * 32 + quad * 8];
        wf[i] = *(const bf16x8*)&Ws[kk * 4096 + (wc + i * 16 + n16) * 32 + quad * 8];
      }
      #pragma unroll
      for (int i = 0; i < 4; ++i)
        #pragma unroll
        for (int j = 0; j < 4; ++j)
          acc[i][j] = __builtin_amdgcn_mfma_f32_16x16x32_bf16(af[i], wf[j], acc[i][j], 0, 0, 0);
    }
    __syncthreads();
  }

  if (MODE == 0) {
    #pragma unroll
    for (int i = 0; i < 4; ++i)
      #pragma unroll
      for (int r = 0; r < 4; ++r) {
        size_t row = (size_t)(bm + wr + i * 16 + quad * 4 + r);
        #pragma unroll
        for (int j = 0; j < 4; ++j)
          ((float*)Cout)[row * N + bn + wc + j * 16 + n16] = acc[i][j][r];
      }
  } else if (MODE == 2) {
    // q_up: rope last 64 of each 192-head, scale, pack to (b,h,s,192)
    #pragma unroll
    for (int i = 0; i < 4; ++i)
      #pragma unroll
      for (int r = 0; r < 4; ++r) {
        int m = bm + wr + i * 16 + quad * 4 + r;
        int bb = m >> 11, s = m & 2047;
        #pragma unroll
        for (int j = 0; j < 4; ++j) {
          int col = bn + wc + j * 16 + n16;
          int h = col / 192, c = col - h * 192;
          float v = acc[i][j][r];
          if (c >= 128) {
            int jr = c - 128;
            float part = acc[i][j ^ 2][r];   // partner col = col +/- 32 (in-wave)
            float cs = cosb[(size_t)m * 64 + jr], sn = sinb[(size_t)m * 64 + jr];
            v = (jr < 32) ? (v * cs - part * sn) : (v * cs + part * sn);
          }
          ((short*)Cout)[(((size_t)(bb * 16 + h)) * 2048 + s) * 192 + c] = f2bf(v * SCALE_F);
        }
      }
  } else if (MODE == 3) {
    // kv_up: N=4096, head = col>>8; c<128 -> Kb nope, c>=128 -> Vt transposed
    #pragma unroll
    for (int i = 0; i < 4; ++i)
      #pragma unroll
      for (int r = 0; r < 4; ++r) {
        int m = bm + wr + i * 16 + quad * 4 + r;
        int bb = m >> 11, s = m & 2047;
        #pragma unroll
        for (int j = 0; j < 4; ++j) {
          int col = bn + wc + j * 16 + n16;
          int h = col >> 8, c = col & 255;
          short v = f2bf(acc[i][j][r]);
          if (c < 128)
            ((short*)Cout)[(((size_t)(bb * 16 + h)) * 2048 + s) * 192 + c] = v;
          else
            out2[((size_t)(bb * 16 + h) * 128 + (c - 128)) * 2048 + s] = v;
        }
      }
    // fused krope_fill: nope tiles copy rope cols for (head h, rows bm..bm+127)
    if ((bn & 255) == 0) {
      const short* kr = (const short*)sinb;
      const int h = bn >> 8;
      const int bb = bm >> 11, sb = bm & 2047;
      const int rr = tid >> 1, half = tid & 1;
      const short* src = kr + (size_t)(bm + rr) * 64 + half * 32;
      short* dst = (short*)Cout + (((size_t)(bb * 16 + h)) * 2048 + sb + rr) * 192 + 128 + half * 32;
      #pragma unroll
      for (int k = 0; k < 4; ++k)
        *(bf16x8*)(dst + k * 8) = *(const bf16x8*)(src + k * 8);
    }
  } else {
    // MODE 4: merged down-proj split output (tile-uniform: col<1536 -> q_lat)
    float* qlat = (float*)Cout;
    float* kvf  = (float*)out2;
    #pragma unroll
    for (int i = 0; i < 4; ++i)
      #pragma unroll
      for (int r = 0; r < 4; ++r) {
        size_t row = (size_t)(bm + wr + i * 16 + quad * 4 + r);
        #pragma unroll
        for (int j = 0; j < 4; ++j) {
          int col = bn + wc + j * 16 + n16;
          if (col < 1536) qlat[row * 1536 + col] = acc[i][j][r];
          else            kvf[row * 640 + (col - 1536)] = acc[i][j][r];
        }
      }
  }
}

// ---------------------------------------------------------------------------
// fused fp32 -> bf16 cast of hidden + all 5 weights (one launch)
// ---------------------------------------------------------------------------
__global__ __launch_bounds__(256) void cast_all(
    const float* __restrict__ hidden, const float* __restrict__ Wqd,
    const float* __restrict__ Wqu, const float* __restrict__ Wkvu,
    const float* __restrict__ Wo, const float* __restrict__ Wkvd,
    short* __restrict__ hb, short* __restrict__ Wqd_b, short* __restrict__ Wqu_b,
    short* __restrict__ Wkvu_b, short* __restrict__ Wo_b, short* __restrict__ Wkvd_b)
{
  int blk = blockIdx.x;
  const float* src; short* dst; int i;
  if (blk < 8192)       { src = hidden; dst = hb;     i = (blk * 256 + threadIdx.x) * 4; }
  else if (blk < 11264) { src = Wqd;  dst = Wqd_b;  i = ((blk - 8192) * 256 + threadIdx.x) * 4; }
  else if (blk < 15872) { src = Wqu;  dst = Wqu_b;  i = ((blk - 11264) * 256 + threadIdx.x) * 4; }
  else if (blk < 17920) { src = Wkvu; dst = Wkvu_b; i = ((blk - 15872) * 256 + threadIdx.x) * 4; }
  else if (blk < 22016) { src = Wo;   dst = Wo_b;   i = ((blk - 17920) * 256 + threadIdx.x) * 4; }
  else {
    i = ((blk - 22016) * 256 + threadIdx.x) * 4;
    int r = i >> 11;
    short4 o = {0, 0, 0, 0};
    if (r < 576) {
      float4 v = *(const float4*)(Wkvd + i);
      o.x = f2bf(v.x); o.y = f2bf(v.y); o.z = f2bf(v.z); o.w = f2bf(v.w);
    }
    *(short4*)(Wkvd_b + i) = o;
    return;
  }
  float4 v = *(const float4*)(src + i);
  short4 o = { f2bf(v.x), f2bf(v.y), f2bf(v.z), f2bf(v.w) };
  *(short4*)(dst + i) = o;
}

// ---------------------------------------------------------------------------
// merged RMSNorm: blocks <4096 -> q_lat (C=1536); blocks >=4096 -> kv + rope
// ---------------------------------------------------------------------------
__global__ __launch_bounds__(256) void rmsnorm_both(
    const float* __restrict__ q_lat, const float* __restrict__ q_gamma,
    short* __restrict__ q_lat_b,
    const float* __restrict__ kvf, const float* __restrict__ kv_gamma,
    const float* __restrict__ cosb, const float* __restrict__ sinb,
    short* __restrict__ ckv, short* __restrict__ kr)
{
  const int tid = threadIdx.x;
  __shared__ float red[4];
  if (blockIdx.x < 4096) {
    const int m = blockIdx.x;
    const float* x = q_lat + (size_t)m * 1536;
    short* y = q_lat_b + (size_t)m * 1536;
    float ss = 0.f;
    for (int c = tid * 4; c < 1536; c += 1024) {
      float4 v = *(const float4*)(x + c);
      ss += v.x * v.x + v.y * v.y + v.z * v.z + v.w * v.w;
    }
    #pragma unroll
    for (int off = 32; off > 0; off >>= 1) ss += __shfl_down(ss, off, 64);
    if ((tid & 63) == 0) red[tid >> 6] = ss;
    __syncthreads();
    float tot = red[0] + red[1] + red[2] + red[3];
    float scale = rsqrtf(tot / 1536.f + 1e-6f);
    for (int c = tid * 4; c < 1536; c += 1024) {
      float4 v = *(const float4*)(x + c);
      float4 g = *(const float4*)(q_gamma + c);
      short4 o = { f2bf(v.x * scale * g.x), f2bf(v.y * scale * g.y),
                   f2bf(v.z * scale * g.z), f2bf(v.w * scale * g.w) };
      *(short4*)(y + c) = o;
    }
  } else {
    const int m = blockIdx.x - 4096;
    const float* x = kvf + (size_t)m * 640;
    short* y = ckv + (size_t)m * 512;
    float ss = 0.f;
    for (int c = tid * 4; c < 512; c += 1024) {
      float4 v = *(const float4*)(x + c);
      ss += v.x * v.x + v.y * v.y + v.z * v.z + v.w * v.w;
    }
    #pragma unroll
    for (int off = 32; off > 0; off >>= 1) ss += __shfl_down(ss, off, 64);
    if ((tid & 63) == 0) red[tid >> 6] = ss;
    __syncthreads();
    float tot = red[0] + red[1] + red[2] + red[3];
    float scale = rsqrtf(tot / 512.f + 1e-6f);
    for (int c = tid * 4; c < 512; c += 1024) {
      float4 v = *(const float4*)(x + c);
      float4 g = *(const float4*)(kv_gamma + c);
      short4 o = { f2bf(v.x * scale * g.x), f2bf(v.y * scale * g.y),
                   f2bf(v.z * scale * g.z), f2bf(v.w * scale * g.w) };
      *(short4*)(y + c) = o;
    }
    if (tid < 32) {
      const float* cb = cosb + (size_t)m * 64;
      const float* sb = sinb + (size_t)m * 64;
      float x1 = x[512 + tid], x2 = x[512 + tid + 32];
      kr[(size_t)m * 64 + tid]      = f2bf(x1 * cb[tid] - x2 * sb[tid]);
      kr[(size_t)m * 64 + tid + 32] = f2bf(x2 * cb[tid + 32] + x1 * sb[tid + 32]);
    }
  }
}

// ---------------------------------------------------------------------------
// MFMA flash attention v10: split-kt balanced schedule (R4-verified, 81 us).
// ---------------------------------------------------------------------------
#define PSTR 72

__global__ __launch_bounds__(512) void flash_mfma(
    const short* __restrict__ Qb, const short* __restrict__ Kb,
    const short* __restrict__ Vt, short* __restrict__ attnb)
{
  __shared__ __align__(16) short KVs[2][40 * 512];   // per group: 24 K + 16 V chunks (80 KB)
  __shared__ __align__(16) short Ps[8][32 * PSTR];   // 36.9 KB   (total 116.9 KB)

  const int h = blockIdx.x;                          // XCD locality: id%8 = h%8
  const int p = blockIdx.y;                          // pair index 0..7
  const int b = blockIdx.z;
  const int bh = b * 16 + h;
  const int tid = threadIdx.x;
  const int wave = tid >> 6, lane = tid & 63;
  const int grp = wave >> 2, w4 = wave & 3;          // grp0 heavy / grp1 light->heavy
  const int quad = lane >> 4, n16 = lane & 15;
  const int lq = lane >> 2, lr = lane & 3;           // staging lane split
  const int qt_h = 15 - p;
  const int L = 2 * p + 2;                           // light-tile iteration count
  const int NIT = 17;                                // iterations for every wave

  int qw = (grp ? p : qt_h) * 128 + w4 * 32;         // current tile q-window

  const short* kS[6]; short* kD[6];
  #pragma unroll
  for (int u = 0; u < 6; ++u) {
    kS[u] = Kb + ((size_t)bh * 2048 + w4 * 16 + lq) * 192 + u * 32 + lr * 8;
    kD[u] = &KVs[grp][(w4 * 6 + u) * 512 + lane * 8];
  }
  const short* vS[4]; short* vD[4];
  #pragma unroll
  for (int u = 0; u < 4; ++u) {
    int ci = w4 * 4 + u, ks = ci >> 3, vt = ci & 7;
    vS[u] = Vt + ((size_t)bh * 128 + vt * 16 + lq) * 2048 + ks * 32 + lr * 8;
    vD[u] = &KVs[grp][(24 + ci) * 512 + lane * 8];
  }

  bf16x8 aQ[2][6];
  #pragma unroll
  for (int rg = 0; rg < 2; ++rg) {
    const short* qp = Qb + ((size_t)bh * 2048 + qw + rg * 16 + n16) * 192 + quad * 8;
    #pragma unroll
    for (int t = 0; t < 6; ++t) aQ[rg][t] = *(const bf16x8*)(qp + t * 32);
  }

  f32x4 O[2][8];
  #pragma unroll
  for (int rg = 0; rg < 2; ++rg)
    #pragma unroll
    for (int i = 0; i < 8; ++i) O[rg][i] = (f32x4){0.f, 0.f, 0.f, 0.f};
  float lp[2] = {0.f, 0.f};

  short* pw = &Ps[wave][0];

  {
    #pragma unroll
    for (int u = 0; u < 6; ++u) gl_lds16(kS[u], kD[u]);
    #pragma unroll
    for (int u = 0; u < 4; ++u) gl_lds16(vS[u], vD[u]);
  }

  for (int j = 0; j < NIT; ++j) {
    __syncthreads();   // stage(j) complete (barrier drains vmcnt)

    if (grp == 1 && j == L) {
      #pragma unroll
      for (int rg = 0; rg < 2; ++rg) {
        float l = lp[rg];
        l += __shfl_xor(l, 16);
        l += __shfl_xor(l, 32);
        float inv_l[4];
        #pragma unroll
        for (int r = 0; r < 4; ++r) inv_l[r] = 1.f / __shfl(l, quad * 4 + r);
        #pragma unroll
        for (int vt = 0; vt < 8; ++vt)
          #pragma unroll
          for (int r = 0; r < 4; ++r) {
            size_t m = (size_t)b * 2048 + qw + rg * 16 + quad * 4 + r;
            attnb[(m * 16 + h) * 128 + vt * 16 + n16] = f2bf(O[rg][vt][r] * inv_l[r]);
          }
      }
      #pragma unroll
      for (int rg = 0; rg < 2; ++rg)
        #pragma unroll
        for (int i = 0; i < 8; ++i) O[rg][i] = (f32x4){0.f, 0.f, 0.f, 0.f};
      lp[0] = 0.f; lp[1] = 0.f;
      qw = qt_h * 128 + w4 * 32;
      #pragma unroll
      for (int rg = 0; rg < 2; ++rg) {
        const short* qp = Qb + ((size_t)bh * 2048 + qw + rg * 16 + n16) * 192 + quad * 8;
        #pragma unroll
        for (int t = 0; t < 6; ++t) aQ[rg][t] = *(const bf16x8*)(qp + t * 32);
      }
    }

    const int kt = (grp == 0) ? j : (j < L ? j : 17 + j - L);

    if (kt * 64 <= qw + 31) {
      float s[4][2][4];
      bool act[4];
      const bool tail = (kt * 64 + 63 > qw);
      #pragma unroll
      for (int ct = 0; ct < 4; ++ct) {
        act[ct] = (kt * 64 + ct * 16 <= qw + 31);
        if (act[ct]) {
          f32x4 a0 = (f32x4){0.f, 0.f, 0.f, 0.f};
          f32x4 a1 = (f32x4){0.f, 0.f, 0.f, 0.f};
          #pragma unroll
          for (int t = 0; t < 6; ++t) {
            bf16x8 ak = *(const bf16x8*)&KVs[grp][(ct * 6 + t) * 512 + n16 * 32 + quad * 8];
            a0 = __builtin_amdgcn_mfma_f32_16x16x32_bf16(ak, aQ[0][t], a0, 0, 0, 0);
            a1 = __builtin_amdgcn_mfma_f32_16x16x32_bf16(ak, aQ[1][t], a1, 0, 0, 0);
          }
          #pragma unroll
          for (int r = 0; r < 4; ++r) { s[ct][0][r] = a0[r]; s[ct][1][r] = a1[r]; }
        }
      }

      #pragma unroll
      for (int rg = 0; rg < 2; ++rg) {
        const int q = qw + rg * 16 + n16;
        #pragma unroll
        for (int ct = 0; ct < 4; ++ct) {
          u16x4 pk;
          #pragma unroll
          for (int r = 0; r < 4; ++r) {
            float v = 0.f;
            if (act[ct]) {
              v = __expf(s[ct][rg][r]);
              if (tail) {
                int key = kt * 64 + ct * 16 + quad * 4 + r;
                if (key > q) v = 0.f;
              }
            }
            lp[rg] += v;
            pk[r] = (unsigned short)f2bf(v);
          }
          *(u16x4*)&pw[(rg * 16 + n16) * PSTR + ct * 16 + quad * 4] = pk;
        }
      }

      #pragma unroll
      for (int ks = 0; ks < 2; ++ks) {
        if (kt * 64 + ks * 32 <= qw + 31) {
          bf16x8 aP0 = *(const bf16x8*)&pw[(n16) * PSTR + ks * 32 + quad * 8];
          bf16x8 aP1 = *(const bf16x8*)&pw[(16 + n16) * PSTR + ks * 32 + quad * 8];
          #pragma unroll
          for (int vt = 0; vt < 8; ++vt) {
            bf16x8 bV = *(const bf16x8*)&KVs[grp][(24 + ks * 8 + vt) * 512 + n16 * 32 + quad * 8];
            O[0][vt] = __builtin_amdgcn_mfma_f32_16x16x32_bf16(aP0, bV, O[0][vt], 0, 0, 0);
            O[1][vt] = __builtin_amdgcn_mfma_f32_16x16x32_bf16(aP1, bV, O[1][vt], 0, 0, 0);
          }
        }
      }
    }

    __syncthreads();   // readers of KVs[grp] done

    if (j + 1 < NIT) {
      const int jn = j + 1;
      const int ktn = (grp == 0) ? jn : (jn < L ? jn : 17 + jn - L);
      const size_t ka = (size_t)ktn * (64 * 192);
      const size_t va = (size_t)ktn * 64;
      #pragma unroll
      for (int u = 0; u < 6; ++u) gl_lds16(kS[u] + ka, kD[u]);
      #pragma unroll
      for (int u = 0; u < 4; ++u) gl_lds16(vS[u] + va, vD[u]);
    }
  }

  // ---- epilogue: combine grp1's heavy partial into grp0, store heavy ----
  float* xO = (float*)&KVs[0][0];
  float* xl = (float*)&Ps[0][0];
  const int xb = w4 * 4160 + lane * 65;      // stride 65 -> conflict-free
  if (grp == 1) {
    #pragma unroll
    for (int rg = 0; rg < 2; ++rg)
      #pragma unroll
      for (int vt = 0; vt < 8; ++vt)
        #pragma unroll
        for (int r = 0; r < 4; ++r)
          xO[xb + rg * 32 + vt * 4 + r] = O[rg][vt][r];
    xl[w4 * 128 + lane * 2 + 0] = lp[0];
    xl[w4 * 128 + lane * 2 + 1] = lp[1];
  }
  __syncthreads();
  if (grp == 0) {
    #pragma unroll
    for (int rg = 0; rg < 2; ++rg)
      #pragma unroll
      for (int vt = 0; vt < 8; ++vt)
        #pragma unroll
        for (int r = 0; r < 4; ++r)
          O[rg][vt][r] += xO[xb + rg * 32 + vt * 4 + r];
    lp[0] += xl[w4 * 128 + lane * 2 + 0];
    lp[1] += xl[w4 * 128 + lane * 2 + 1];

    #pragma unroll
    for (int rg = 0; rg < 2; ++rg) {
      float l = lp[rg];
      l += __shfl_xor(l, 16);
      l += __shfl_xor(l, 32);
      float inv_l[4];
      #pragma unroll
      for (int r = 0; r < 4; ++r) inv_l[r] = 1.f / __shfl(l, quad * 4 + r);
      #pragma unroll
      for (int vt = 0; vt < 8; ++vt)
        #pragma unroll
        for (int r = 0; r < 4; ++r) {
          size_t m = (size_t)b * 2048 + qw + rg * 16 + quad * 4 + r;
          attnb[(m * 16 + h) * 128 + vt * 16 + n16] = f2bf(O[rg][vt][r] * inv_l[r]);
        }
    }
  }
}

// ---------------------------------------------------------------------------
extern "C" void kernel_launch(void* const* d_in, const int* in_sizes, int n_in,
                              void* d_out, int out_size, void* d_ws, size_t ws_size,
                              hipStream_t stream)
{
  const float* hidden   = (const float*)d_in[0];
  const float* cosb     = (const float*)d_in[1];
  const float* sinb     = (const float*)d_in[2];
  const float* Wq_down  = (const float*)d_in[3];
  const float* q_gamma  = (const float*)d_in[4];
  const float* Wq_up    = (const float*)d_in[5];
  const float* Wkv_down = (const float*)d_in[6];
  const float* kv_gamma = (const float*)d_in[7];
  const float* Wkv_up   = (const float*)d_in[8];
  const float* Wo       = (const float*)d_in[9];
  float* out = (float*)d_out;

  // ---- workspace (117 MB, aliased; liveness unchanged) ----
  char* base = (char*)d_ws;
  short* hb  = (short*)base;
  float* kvf = (float*)(base + 16777216);
  short* Qb  = (short*)base;
  char* pB = base + 27262976;
  short* Wqd_b  = (short*)pB;                       // [2176][2048] with Wkvd_b
  short* Wkvd_b = (short*)(pB + 6291456);
  short* Wqu_b  = (short*)(pB + 8912896);
  short* Wkvu_b = (short*)(pB + 18350080);
  short* Wo_b   = (short*)(pB + 22544384);
  char* pC = pB + 30932992;
  float* q_lat = (float*)pC;
  short* Kb    = (short*)pC;
  char* pD = pC + 25165824;
  short* q_lat_b = (short*)pD;
  short* ckv_b   = (short*)(pD + 12582912);
  short* krope_b = (short*)(pD + 16777216);
  short* attn_b  = (short*)pD;
  char* pE = pD + 17301504;
  short* Vt = (short*)pE;

  dim3 blk(256);

  cast_all<<<23296, blk, 0, stream>>>(hidden, Wq_down, Wq_up, Wkv_up, Wo, Wkv_down,
                                      hb, Wqd_b, Wqu_b, Wkvu_b, Wo_b, Wkvd_b);

  // merged down-proj: N=2176 (Wqd_b|Wkvd_b contiguous), split fp32 outputs
  gemm_mfma<4><<<dim3(17, 32), blk, 0, stream>>>(hb, Wqd_b, q_lat, 2176, 2048,
                                                 nullptr, nullptr, (short*)kvf);

  rmsnorm_both<<<8192, blk, 0, stream>>>(q_lat, q_gamma, q_lat_b,
                                         kvf, kv_gamma, cosb, sinb, ckv_b, krope_b);

  // separate up-proj launches (co-launch twice-falsified: R5 228us, R7 216us)
  gemm_mfma<2><<<dim3(24, 32), blk, 0, stream>>>(q_lat_b, Wqu_b, Qb, 3072, 1536,
                                                 cosb, sinb, nullptr);
  gemm_mfma<3><<<dim3(32, 32), blk, 0, stream>>>(ckv_b, Wkvu_b, Kb, 4096, 512,
                                                 nullptr, (const float*)krope_b, Vt);

  flash_mfma<<<dim3(16, 8, 2), dim3(512), 0, stream>>>(Qb, Kb, Vt, attn_b);
  gemm_mfma<0><<<dim3(16, 32), blk, 0, stream>>>(attn_b, Wo_b, out, 2048, 2048,
                                                 nullptr, nullptr, nullptr);
}

// Round 9
// 467.955 us; speedup vs baseline: 1.1973x; 1.0579x over previous
//
#include <hip/hip_runtime.h>
#include <math.h>

#define SCALE_F 0.0721687836487032f  // 192^-0.5

typedef __attribute__((ext_vector_type(8))) short bf16x8;
typedef __attribute__((ext_vector_type(4))) float f32x4;
typedef __attribute__((ext_vector_type(4))) unsigned short u16x4;

static __device__ __forceinline__ short f2bf(float f) {
  unsigned u = __float_as_uint(f);
  u += 0x7fffu + ((u >> 16) & 1u);   // RNE
  return (short)(u >> 16);
}

// async global->LDS, 16B per lane (m97-verified path)
static __device__ __forceinline__ void gl_lds16(const void* g, void* l) {
  __builtin_amdgcn_global_load_lds((const __attribute__((address_space(1))) void*)g,
                                   (__attribute__((address_space(3))) void*)l, 16, 0, 0);
}

// ---------------------------------------------------------------------------
// bf16 MFMA GEMM (m97 structure, R1/R6-verified BK=32 staging — BK=64
// falsified R8: +15% on up-GEMM) + XCD-aware bijective block swizzle (T1):
// hardware XCD = linear_bid % 8; we hand XCD k the contiguous work chunk
// [k*nwg/8, (k+1)*nwg/8) so each XCD's L2 holds only ~4 A-panels (1.6 MB)
// reused across all N-tiles. All grids are %8 == 0. Correctness-neutral.
// MODE 0: fp32 out row-major [M][N]
// MODE 2: q_up fused rope+scale+pack -> Qb (b,h,s,192) bf16   (N=3072)
// MODE 3: kv_up fused split -> Kb nope cols + Vt transposed; nope tiles also
//         fill Kb rope cols from krope (passed via sinb) -> krope_fill fused
// MODE 4: merged down-proj: col<1536 -> q_lat fp32; col>=1536 -> kvf fp32
// ---------------------------------------------------------------------------
template <int MODE>
__global__ __launch_bounds__(256) void gemm_mfma(
    const short* __restrict__ A, const short* __restrict__ W,
    void* __restrict__ Cout, int N, int K,
    const float* __restrict__ cosb, const float* __restrict__ sinb,
    short* __restrict__ out2)
{
  __shared__ __align__(16) short As[128 * 32];
  __shared__ __align__(16) short Ws[128 * 32];
  const int tid = threadIdx.x;
  const int lane = tid & 63;
  const int quad = lane >> 4, n16 = lane & 15;

  // XCD-aware bijective swizzle (nwg % 8 == 0 for all our grids)
  const int nwg = gridDim.x * gridDim.y;
  int bid = blockIdx.y * gridDim.x + blockIdx.x;
  bid = (bid & 7) * (nwg >> 3) + (bid >> 3);
  const int bxi = bid % gridDim.x, byi = bid / gridDim.x;
  const int bm = byi * 128, bn = bxi * 128;

  const int wr = ((tid >> 6) >> 1) * 64, wc = ((tid >> 6) & 1) * 64;

  f32x4 acc[4][4];
  #pragma unroll
  for (int i = 0; i < 4; ++i)
    #pragma unroll
    for (int j = 0; j < 4; ++j) acc[i][j] = (f32x4){0.f, 0.f, 0.f, 0.f};

  const int r0 = tid >> 2, c0 = (tid & 3) * 8;
  const short* a0p = A + (size_t)(bm + r0) * K + c0;
  const short* a1p = A + (size_t)(bm + 64 + r0) * K + c0;
  const short* w0p = W + (size_t)(bn + r0) * K + c0;
  const short* w1p = W + (size_t)(bn + 64 + r0) * K + c0;
  short* asd0 = &As[tid * 8];
  short* asd1 = &As[2048 + tid * 8];
  short* wsd0 = &Ws[tid * 8];
  short* wsd1 = &Ws[2048 + tid * 8];

  for (int k0 = 0; k0 < K; k0 += 32) {
    gl_lds16(a0p, asd0);
    gl_lds16(a1p, asd1);
    gl_lds16(w0p, wsd0);
    gl_lds16(w1p, wsd1);
    a0p += 32; a1p += 32; w0p += 32; w1p += 32;
    __syncthreads();

    bf16x8 af[4], wf[4];
    #pragma unroll
    for (int i = 0; i < 4; ++i) {
      af[i] = *(const bf16x8*)&As[(wr + i * 16 + n16) * 32 + quad * 8];
      wf[i] = *(const bf16x8*)&Ws[(wc + i * 16 + n16) * 32 + quad * 8];
    }
    #pragma unroll
    for (int i = 0; i < 4; ++i)
      #pragma unroll
      for (int j = 0; j < 4; ++j)
        acc[i][j] = __builtin_amdgcn_mfma_f32_16x16x32_bf16(af[i], wf[j], acc[i][j], 0, 0, 0);
    __syncthreads();
  }

  if (MODE == 0) {
    #pragma unroll
    for (int i = 0; i < 4; ++i)
      #pragma unroll
      for (int r = 0; r < 4; ++r) {
        size_t row = (size_t)(bm + wr + i * 16 + quad * 4 + r);
        #pragma unroll
        for (int j = 0; j < 4; ++j)
          ((float*)Cout)[row * N + bn + wc + j * 16 + n16] = acc[i][j][r];
      }
  } else if (MODE == 2) {
    // q_up: rope last 64 of each 192-head, scale, pack to (b,h,s,192)
    #pragma unroll
    for (int i = 0; i < 4; ++i)
      #pragma unroll
      for (int r = 0; r < 4; ++r) {
        int m = bm + wr + i * 16 + quad * 4 + r;
        int bb = m >> 11, s = m & 2047;
        #pragma unroll
        for (int j = 0; j < 4; ++j) {
          int col = bn + wc + j * 16 + n16;
          int h = col / 192, c = col - h * 192;
          float v = acc[i][j][r];
          if (c >= 128) {
            int jr = c - 128;
            float part = acc[i][j ^ 2][r];   // partner col = col +/- 32 (in-wave)
            float cs = cosb[(size_t)m * 64 + jr], sn = sinb[(size_t)m * 64 + jr];
            v = (jr < 32) ? (v * cs - part * sn) : (v * cs + part * sn);
          }
          ((short*)Cout)[(((size_t)(bb * 16 + h)) * 2048 + s) * 192 + c] = f2bf(v * SCALE_F);
        }
      }
  } else if (MODE == 3) {
    // kv_up: N=4096, head = col>>8; c<128 -> Kb nope, c>=128 -> Vt transposed
    #pragma unroll
    for (int i = 0; i < 4; ++i)
      #pragma unroll
      for (int r = 0; r < 4; ++r) {
        int m = bm + wr + i * 16 + quad * 4 + r;
        int bb = m >> 11, s = m & 2047;
        #pragma unroll
        for (int j = 0; j < 4; ++j) {
          int col = bn + wc + j * 16 + n16;
          int h = col >> 8, c = col & 255;
          short v = f2bf(acc[i][j][r]);
          if (c < 128)
            ((short*)Cout)[(((size_t)(bb * 16 + h)) * 2048 + s) * 192 + c] = v;
          else
            out2[((size_t)(bb * 16 + h) * 128 + (c - 128)) * 2048 + s] = v;
        }
      }
    // fused krope_fill: nope tiles copy rope cols for (head h, rows bm..bm+127)
    if ((bn & 255) == 0) {
      const short* kr = (const short*)sinb;
      const int h = bn >> 8;
      const int bb = bm >> 11, sb = bm & 2047;
      const int rr = tid >> 1, half = tid & 1;
      const short* src = kr + (size_t)(bm + rr) * 64 + half * 32;
      short* dst = (short*)Cout + (((size_t)(bb * 16 + h)) * 2048 + sb + rr) * 192 + 128 + half * 32;
      #pragma unroll
      for (int k = 0; k < 4; ++k)
        *(bf16x8*)(dst + k * 8) = *(const bf16x8*)(src + k * 8);
    }
  } else {
    // MODE 4: merged down-proj split output (tile-uniform: col<1536 -> q_lat)
    float* qlat = (float*)Cout;
    float* kvf  = (float*)out2;
    #pragma unroll
    for (int i = 0; i < 4; ++i)
      #pragma unroll
      for (int r = 0; r < 4; ++r) {
        size_t row = (size_t)(bm + wr + i * 16 + quad * 4 + r);
        #pragma unroll
        for (int j = 0; j < 4; ++j) {
          int col = bn + wc + j * 16 + n16;
          if (col < 1536) qlat[row * 1536 + col] = acc[i][j][r];
          else            kvf[row * 640 + (col - 1536)] = acc[i][j][r];
        }
      }
  }
}

// ---------------------------------------------------------------------------
// fused fp32 -> bf16 cast of hidden + all 5 weights (one launch)
// ---------------------------------------------------------------------------
__global__ __launch_bounds__(256) void cast_all(
    const float* __restrict__ hidden, const float* __restrict__ Wqd,
    const float* __restrict__ Wqu, const float* __restrict__ Wkvu,
    const float* __restrict__ Wo, const float* __restrict__ Wkvd,
    short* __restrict__ hb, short* __restrict__ Wqd_b, short* __restrict__ Wqu_b,
    short* __restrict__ Wkvu_b, short* __restrict__ Wo_b, short* __restrict__ Wkvd_b)
{
  int blk = blockIdx.x;
  const float* src; short* dst; int i;
  if (blk < 8192)       { src = hidden; dst = hb;     i = (blk * 256 + threadIdx.x) * 4; }
  else if (blk < 11264) { src = Wqd;  dst = Wqd_b;  i = ((blk - 8192) * 256 + threadIdx.x) * 4; }
  else if (blk < 15872) { src = Wqu;  dst = Wqu_b;  i = ((blk - 11264) * 256 + threadIdx.x) * 4; }
  else if (blk < 17920) { src = Wkvu; dst = Wkvu_b; i = ((blk - 15872) * 256 + threadIdx.x) * 4; }
  else if (blk < 22016) { src = Wo;   dst = Wo_b;   i = ((blk - 17920) * 256 + threadIdx.x) * 4; }
  else {
    i = ((blk - 22016) * 256 + threadIdx.x) * 4;
    int r = i >> 11;
    short4 o = {0, 0, 0, 0};
    if (r < 576) {
      float4 v = *(const float4*)(Wkvd + i);
      o.x = f2bf(v.x); o.y = f2bf(v.y); o.z = f2bf(v.z); o.w = f2bf(v.w);
    }
    *(short4*)(Wkvd_b + i) = o;
    return;
  }
  float4 v = *(const float4*)(src + i);
  short4 o = { f2bf(v.x), f2bf(v.y), f2bf(v.z), f2bf(v.w) };
  *(short4*)(dst + i) = o;
}

// ---------------------------------------------------------------------------
// merged RMSNorm: blocks <4096 -> q_lat (C=1536); blocks >=4096 -> kv + rope
// ---------------------------------------------------------------------------
__global__ __launch_bounds__(256) void rmsnorm_both(
    const float* __restrict__ q_lat, const float* __restrict__ q_gamma,
    short* __restrict__ q_lat_b,
    const float* __restrict__ kvf, const float* __restrict__ kv_gamma,
    const float* __restrict__ cosb, const float* __restrict__ sinb,
    short* __restrict__ ckv, short* __restrict__ kr)
{
  const int tid = threadIdx.x;
  __shared__ float red[4];
  if (blockIdx.x < 4096) {
    const int m = blockIdx.x;
    const float* x = q_lat + (size_t)m * 1536;
    short* y = q_lat_b + (size_t)m * 1536;
    float ss = 0.f;
    for (int c = tid * 4; c < 1536; c += 1024) {
      float4 v = *(const float4*)(x + c);
      ss += v.x * v.x + v.y * v.y + v.z * v.z + v.w * v.w;
    }
    #pragma unroll
    for (int off = 32; off > 0; off >>= 1) ss += __shfl_down(ss, off, 64);
    if ((tid & 63) == 0) red[tid >> 6] = ss;
    __syncthreads();
    float tot = red[0] + red[1] + red[2] + red[3];
    float scale = rsqrtf(tot / 1536.f + 1e-6f);
    for (int c = tid * 4; c < 1536; c += 1024) {
      float4 v = *(const float4*)(x + c);
      float4 g = *(const float4*)(q_gamma + c);
      short4 o = { f2bf(v.x * scale * g.x), f2bf(v.y * scale * g.y),
                   f2bf(v.z * scale * g.z), f2bf(v.w * scale * g.w) };
      *(short4*)(y + c) = o;
    }
  } else {
    const int m = blockIdx.x - 4096;
    const float* x = kvf + (size_t)m * 640;
    short* y = ckv + (size_t)m * 512;
    float ss = 0.f;
    for (int c = tid * 4; c < 512; c += 1024) {
      float4 v = *(const float4*)(x + c);
      ss += v.x * v.x + v.y * v.y + v.z * v.z + v.w * v.w;
    }
    #pragma unroll
    for (int off = 32; off > 0; off >>= 1) ss += __shfl_down(ss, off, 64);
    if ((tid & 63) == 0) red[tid >> 6] = ss;
    __syncthreads();
    float tot = red[0] + red[1] + red[2] + red[3];
    float scale = rsqrtf(tot / 512.f + 1e-6f);
    for (int c = tid * 4; c < 512; c += 1024) {
      float4 v = *(const float4*)(x + c);
      float4 g = *(const float4*)(kv_gamma + c);
      short4 o = { f2bf(v.x * scale * g.x), f2bf(v.y * scale * g.y),
                   f2bf(v.z * scale * g.z), f2bf(v.w * scale * g.w) };
      *(short4*)(y + c) = o;
    }
    if (tid < 32) {
      const float* cb = cosb + (size_t)m * 64;
      const float* sb = sinb + (size_t)m * 64;
      float x1 = x[512 + tid], x2 = x[512 + tid + 32];
      kr[(size_t)m * 64 + tid]      = f2bf(x1 * cb[tid] - x2 * sb[tid]);
      kr[(size_t)m * 64 + tid + 32] = f2bf(x2 * cb[tid + 32] + x1 * sb[tid + 32]);
    }
  }
}

// ---------------------------------------------------------------------------
// MFMA flash attention v10: split-kt balanced schedule (R4-verified, 81 us).
// ---------------------------------------------------------------------------
#define PSTR 72

__global__ __launch_bounds__(512) void flash_mfma(
    const short* __restrict__ Qb, const short* __restrict__ Kb,
    const short* __restrict__ Vt, short* __restrict__ attnb)
{
  __shared__ __align__(16) short KVs[2][40 * 512];   // per group: 24 K + 16 V chunks (80 KB)
  __shared__ __align__(16) short Ps[8][32 * PSTR];   // 36.9 KB   (total 116.9 KB)

  const int h = blockIdx.x;                          // XCD locality: id%8 = h%8
  const int p = blockIdx.y;                          // pair index 0..7
  const int b = blockIdx.z;
  const int bh = b * 16 + h;
  const int tid = threadIdx.x;
  const int wave = tid >> 6, lane = tid & 63;
  const int grp = wave >> 2, w4 = wave & 3;          // grp0 heavy / grp1 light->heavy
  const int quad = lane >> 4, n16 = lane & 15;
  const int lq = lane >> 2, lr = lane & 3;           // staging lane split
  const int qt_h = 15 - p;
  const int L = 2 * p + 2;                           // light-tile iteration count
  const int NIT = 17;                                // iterations for every wave

  int qw = (grp ? p : qt_h) * 128 + w4 * 32;         // current tile q-window

  const short* kS[6]; short* kD[6];
  #pragma unroll
  for (int u = 0; u < 6; ++u) {
    kS[u] = Kb + ((size_t)bh * 2048 + w4 * 16 + lq) * 192 + u * 32 + lr * 8;
    kD[u] = &KVs[grp][(w4 * 6 + u) * 512 + lane * 8];
  }
  const short* vS[4]; short* vD[4];
  #pragma unroll
  for (int u = 0; u < 4; ++u) {
    int ci = w4 * 4 + u, ks = ci >> 3, vt = ci & 7;
    vS[u] = Vt + ((size_t)bh * 128 + vt * 16 + lq) * 2048 + ks * 32 + lr * 8;
    vD[u] = &KVs[grp][(24 + ci) * 512 + lane * 8];
  }

  bf16x8 aQ[2][6];
  #pragma unroll
  for (int rg = 0; rg < 2; ++rg) {
    const short* qp = Qb + ((size_t)bh * 2048 + qw + rg * 16 + n16) * 192 + quad * 8;
    #pragma unroll
    for (int t = 0; t < 6; ++t) aQ[rg][t] = *(const bf16x8*)(qp + t * 32);
  }

  f32x4 O[2][8];
  #pragma unroll
  for (int rg = 0; rg < 2; ++rg)
    #pragma unroll
    for (int i = 0; i < 8; ++i) O[rg][i] = (f32x4){0.f, 0.f, 0.f, 0.f};
  float lp[2] = {0.f, 0.f};

  short* pw = &Ps[wave][0];

  {
    #pragma unroll
    for (int u = 0; u < 6; ++u) gl_lds16(kS[u], kD[u]);
    #pragma unroll
    for (int u = 0; u < 4; ++u) gl_lds16(vS[u], vD[u]);
  }

  for (int j = 0; j < NIT; ++j) {
    __syncthreads();   // stage(j) complete (barrier drains vmcnt)

    if (grp == 1 && j == L) {
      #pragma unroll
      for (int rg = 0; rg < 2; ++rg) {
        float l = lp[rg];
        l += __shfl_xor(l, 16);
        l += __shfl_xor(l, 32);
        float inv_l[4];
        #pragma unroll
        for (int r = 0; r < 4; ++r) inv_l[r] = 1.f / __shfl(l, quad * 4 + r);
        #pragma unroll
        for (int vt = 0; vt < 8; ++vt)
          #pragma unroll
          for (int r = 0; r < 4; ++r) {
            size_t m = (size_t)b * 2048 + qw + rg * 16 + quad * 4 + r;
            attnb[(m * 16 + h) * 128 + vt * 16 + n16] = f2bf(O[rg][vt][r] * inv_l[r]);
          }
      }
      #pragma unroll
      for (int rg = 0; rg < 2; ++rg)
        #pragma unroll
        for (int i = 0; i < 8; ++i) O[rg][i] = (f32x4){0.f, 0.f, 0.f, 0.f};
      lp[0] = 0.f; lp[1] = 0.f;
      qw = qt_h * 128 + w4 * 32;
      #pragma unroll
      for (int rg = 0; rg < 2; ++rg) {
        const short* qp = Qb + ((size_t)bh * 2048 + qw + rg * 16 + n16) * 192 + quad * 8;
        #pragma unroll
        for (int t = 0; t < 6; ++t) aQ[rg][t] = *(const bf16x8*)(qp + t * 32);
      }
    }

    const int kt = (grp == 0) ? j : (j < L ? j : 17 + j - L);

    if (kt * 64 <= qw + 31) {
      float s[4][2][4];
      bool act[4];
      const bool tail = (kt * 64 + 63 > qw);
      #pragma unroll
      for (int ct = 0; ct < 4; ++ct) {
        act[ct] = (kt * 64 + ct * 16 <= qw + 31);
        if (act[ct]) {
          f32x4 a0 = (f32x4){0.f, 0.f, 0.f, 0.f};
          f32x4 a1 = (f32x4){0.f, 0.f, 0.f, 0.f};
          #pragma unroll
          for (int t = 0; t < 6; ++t) {
            bf16x8 ak = *(const bf16x8*)&KVs[grp][(ct * 6 + t) * 512 + n16 * 32 + quad * 8];
            a0 = __builtin_amdgcn_mfma_f32_16x16x32_bf16(ak, aQ[0][t], a0, 0, 0, 0);
            a1 = __builtin_amdgcn_mfma_f32_16x16x32_bf16(ak, aQ[1][t], a1, 0, 0, 0);
          }
          #pragma unroll
          for (int r = 0; r < 4; ++r) { s[ct][0][r] = a0[r]; s[ct][1][r] = a1[r]; }
        }
      }

      #pragma unroll
      for (int rg = 0; rg < 2; ++rg) {
        const int q = qw + rg * 16 + n16;
        #pragma unroll
        for (int ct = 0; ct < 4; ++ct) {
          u16x4 pk;
          #pragma unroll
          for (int r = 0; r < 4; ++r) {
            float v = 0.f;
            if (act[ct]) {
              v = __expf(s[ct][rg][r]);
              if (tail) {
                int key = kt * 64 + ct * 16 + quad * 4 + r;
                if (key > q) v = 0.f;
              }
            }
            lp[rg] += v;
            pk[r] = (unsigned short)f2bf(v);
          }
          *(u16x4*)&pw[(rg * 16 + n16) * PSTR + ct * 16 + quad * 4] = pk;
        }
      }

      #pragma unroll
      for (int ks = 0; ks < 2; ++ks) {
        if (kt * 64 + ks * 32 <= qw + 31) {
          bf16x8 aP0 = *(const bf16x8*)&pw[(n16) * PSTR + ks * 32 + quad * 8];
          bf16x8 aP1 = *(const bf16x8*)&pw[(16 + n16) * PSTR + ks * 32 + quad * 8];
          #pragma unroll
          for (int vt = 0; vt < 8; ++vt) {
            bf16x8 bV = *(const bf16x8*)&KVs[grp][(24 + ks * 8 + vt) * 512 + n16 * 32 + quad * 8];
            O[0][vt] = __builtin_amdgcn_mfma_f32_16x16x32_bf16(aP0, bV, O[0][vt], 0, 0, 0);
            O[1][vt] = __builtin_amdgcn_mfma_f32_16x16x32_bf16(aP1, bV, O[1][vt], 0, 0, 0);
          }
        }
      }
    }

    __syncthreads();   // readers of KVs[grp] done

    if (j + 1 < NIT) {
      const int jn = j + 1;
      const int ktn = (grp == 0) ? jn : (jn < L ? jn : 17 + jn - L);
      const size_t ka = (size_t)ktn * (64 * 192);
      const size_t va = (size_t)ktn * 64;
      #pragma unroll
      for (int u = 0; u < 6; ++u) gl_lds16(kS[u] + ka, kD[u]);
      #pragma unroll
      for (int u = 0; u < 4; ++u) gl_lds16(vS[u] + va, vD[u]);
    }
  }

  // ---- epilogue: combine grp1's heavy partial into grp0, store heavy ----
  float* xO = (float*)&KVs[0][0];
  float* xl = (float*)&Ps[0][0];
  const int xb = w4 * 4160 + lane * 65;      // stride 65 -> conflict-free
  if (grp == 1) {
    #pragma unroll
    for (int rg = 0; rg < 2; ++rg)
      #pragma unroll
      for (int vt = 0; vt < 8; ++vt)
        #pragma unroll
        for (int r = 0; r < 4; ++r)
          xO[xb + rg * 32 + vt * 4 + r] = O[rg][vt][r];
    xl[w4 * 128 + lane * 2 + 0] = lp[0];
    xl[w4 * 128 + lane * 2 + 1] = lp[1];
  }
  __syncthreads();
  if (grp == 0) {
    #pragma unroll
    for (int rg = 0; rg < 2; ++rg)
      #pragma unroll
      for (int vt = 0; vt < 8; ++vt)
        #pragma unroll
        for (int r = 0; r < 4; ++r)
          O[rg][vt][r] += xO[xb + rg * 32 + vt * 4 + r];
    lp[0] += xl[w4 * 128 + lane * 2 + 0];
    lp[1] += xl[w4 * 128 + lane * 2 + 1];

    #pragma unroll
    for (int rg = 0; rg < 2; ++rg) {
      float l = lp[rg];
      l += __shfl_xor(l, 16);
      l += __shfl_xor(l, 32);
      float inv_l[4];
      #pragma unroll
      for (int r = 0; r < 4; ++r) inv_l[r] = 1.f / __shfl(l, quad * 4 + r);
      #pragma unroll
      for (int vt = 0; vt < 8; ++vt)
        #pragma unroll
        for (int r = 0; r < 4; ++r) {
          size_t m = (size_t)b * 2048 + qw + rg * 16 + quad * 4 + r;
          attnb[(m * 16 + h) * 128 + vt * 16 + n16] = f2bf(O[rg][vt][r] * inv_l[r]);
        }
    }
  }
}

// ---------------------------------------------------------------------------
extern "C" void kernel_launch(void* const* d_in, const int* in_sizes, int n_in,
                              void* d_out, int out_size, void* d_ws, size_t ws_size,
                              hipStream_t stream)
{
  const float* hidden   = (const float*)d_in[0];
  const float* cosb     = (const float*)d_in[1];
  const float* sinb     = (const float*)d_in[2];
  const float* Wq_down  = (const float*)d_in[3];
  const float* q_gamma  = (const float*)d_in[4];
  const float* Wq_up    = (const float*)d_in[5];
  const float* Wkv_down = (const float*)d_in[6];
  const float* kv_gamma = (const float*)d_in[7];
  const float* Wkv_up   = (const float*)d_in[8];
  const float* Wo       = (const float*)d_in[9];
  float* out = (float*)d_out;

  // ---- workspace (117 MB, aliased; liveness unchanged) ----
  char* base = (char*)d_ws;
  short* hb  = (short*)base;
  float* kvf = (float*)(base + 16777216);
  short* Qb  = (short*)base;
  char* pB = base + 27262976;
  short* Wqd_b  = (short*)pB;                       // [2176][2048] with Wkvd_b
  short* Wkvd_b = (short*)(pB + 6291456);
  short* Wqu_b  = (short*)(pB + 8912896);
  short* Wkvu_b = (short*)(pB + 18350080);
  short* Wo_b   = (short*)(pB + 22544384);
  char* pC = pB + 30932992;
  float* q_lat = (float*)pC;
  short* Kb    = (short*)pC;
  char* pD = pC + 25165824;
  short* q_lat_b = (short*)pD;
  short* ckv_b   = (short*)(pD + 12582912);
  short* krope_b = (short*)(pD + 16777216);
  short* attn_b  = (short*)pD;
  char* pE = pD + 17301504;
  short* Vt = (short*)pE;

  dim3 blk(256);

  cast_all<<<23296, blk, 0, stream>>>(hidden, Wq_down, Wq_up, Wkv_up, Wo, Wkv_down,
                                      hb, Wqd_b, Wqu_b, Wkvu_b, Wo_b, Wkvd_b);

  // merged down-proj: N=2176 (Wqd_b|Wkvd_b contiguous), split fp32 outputs
  gemm_mfma<4><<<dim3(17, 32), blk, 0, stream>>>(hb, Wqd_b, q_lat, 2176, 2048,
                                                 nullptr, nullptr, (short*)kvf);

  rmsnorm_both<<<8192, blk, 0, stream>>>(q_lat, q_gamma, q_lat_b,
                                         kvf, kv_gamma, cosb, sinb, ckv_b, krope_b);

  // separate up-proj launches (co-launch twice-falsified: R5 228us, R7 216us)
  gemm_mfma<2><<<dim3(24, 32), blk, 0, stream>>>(q_lat_b, Wqu_b, Qb, 3072, 1536,
                                                 cosb, sinb, nullptr);
  gemm_mfma<3><<<dim3(32, 32), blk, 0, stream>>>(ckv_b, Wkvu_b, Kb, 4096, 512,
                                                 nullptr, (const float*)krope_b, Vt);

  flash_mfma<<<dim3(16, 8, 2), dim3(512), 0, stream>>>(Qb, Kb, Vt, attn_b);
  gemm_mfma<0><<<dim3(16, 32), blk, 0, stream>>>(attn_b, Wo_b, out, 2048, 2048,
                                                 nullptr, nullptr, nullptr);
}